// Round 8
// baseline (373.464 us; speedup 1.0000x reference)
//
#include <hip/hip_runtime.h>

#define DI __device__ __forceinline__

typedef short bf16x8 __attribute__((ext_vector_type(8)));
typedef float f32x4  __attribute__((ext_vector_type(4)));

#define MFMA(a,b,c) __builtin_amdgcn_mfma_f32_16x16x32_bf16(a,b,c,0,0,0)

constexpr int    SZ_WT = 512*80;
constexpr int    SZ_WB = 512*96;
constexpr int    SZ_WF = 96*512;
constexpr int    SZ_WG = 512*512;
constexpr int    SZ_WC = 512*512;
constexpr size_t OFF_WT  = 0;
constexpr size_t OFF_WB  = OFF_WT + 3*(size_t)SZ_WT;     // 122880
constexpr size_t OFF_WF  = OFF_WB + 3*(size_t)SZ_WB;     // 270336
constexpr size_t OFF_WG  = OFF_WF + 3*(size_t)SZ_WF;     // 417792
constexpr size_t OFF_WC  = OFF_WG + 3*(size_t)SZ_WG;     // 1204224
constexpr size_t OFF_WH  = OFF_WC + 3*(size_t)SZ_WC;     // 1990656  [512][192] nhw1|dhw1|wtw1
constexpr size_t OFF_WH2 = OFF_WH + (size_t)512*192;     // 2088960  [128][256] blockdiag(nhw2,dhw2)
constexpr size_t WS_TOTAL= OFF_WH2 + (size_t)128*256;    // 2121728 bf16 elems

DI short f2b(float f){ unsigned u; __builtin_memcpy(&u,&f,4); u += 0x7fffu + ((u>>16)&1u); return (short)(u>>16); }
DI float b2f(short s){ unsigned u = ((unsigned)(unsigned short)s)<<16; float f; __builtin_memcpy(&f,&u,4); return f; }
DI float sigm(float x){ return 1.f/(1.f+__expf(-x)); }
DI unsigned pk2(float a, float b){
  return (unsigned)(unsigned short)f2b(a) | ((unsigned)(unsigned short)f2b(b) << 16);
}

// ---------------- weight prepass: fp32 -> bf16 MFMA-B-fragment layout ----------------
// frag element t = ((nt*K32 + kt)*64 + lane)*8 + j  <->  W[kt*32 + (lane>>4)*8 + j][nt*16 + (lane&15)]
__global__ __launch_bounds__(256) void prep_weights(
    const float* __restrict__ pbw,  const float* __restrict__ paw1,
    const float* __restrict__ piw1, const float* __restrict__ pfw,
    const float* __restrict__ pgw,  const float* __restrict__ fcw,
    const float* __restrict__ nhw1, const float* __restrict__ nhw2,
    const float* __restrict__ dhw1, const float* __restrict__ dhw2,
    const float* __restrict__ wtw1, short* __restrict__ ws)
{
  size_t t = (size_t)blockIdx.x*256 + threadIdx.x;
  if (t >= WS_TOTAL) return;
  float v = 0.f;
  if (t < OFF_WB) {                                   // [512][80] = paw1 | piw1, K32=16
    int q=(int)t; int ly=q/SZ_WT; int qq=q%SZ_WT;
    int j=qq&7, lane=(qq>>3)&63, tile=qq>>9, kt=tile&15, nt=tile>>4;
    int k=kt*32+((lane>>4)<<3)+j, n=nt*16+(lane&15);
    v = (n<64) ? paw1[((size_t)ly*512+k)*64+n] : piw1[((size_t)ly*512+k)*16+(n-64)];
  } else if (t < OFF_WF) {                            // [512][96] pbw flat (c=k*32+j), K32=16
    int q=(int)(t-OFF_WB); int ly=q/SZ_WB; int qq=q%SZ_WB;
    int j=qq&7, lane=(qq>>3)&63, tile=qq>>9, kt=tile&15, nt=tile>>4;
    int k=kt*32+((lane>>4)<<3)+j, c=nt*16+(lane&15);
    v = pbw[(((size_t)ly*3+(c>>5))*512+k)*32+(c&31)];
  } else if (t < OFF_WG) {                            // [96][512] pfw, K32=3
    int q=(int)(t-OFF_WF); int ly=q/SZ_WF; int qq=q%SZ_WF;
    int j=qq&7, lane=(qq>>3)&63, tile=qq>>9, kt=tile%3, nt=tile/3;
    int k=kt*32+((lane>>4)<<3)+j, n=nt*16+(lane&15);
    v = pfw[((size_t)ly*96+k)*512+n];
  } else if (t < OFF_WC) {                            // [512][512] pgw
    int q=(int)(t-OFF_WG); int ly=q/SZ_WG; int qq=q%SZ_WG;
    int j=qq&7, lane=(qq>>3)&63, tile=qq>>9, kt=tile&15, nt=tile>>4;
    int k=kt*32+((lane>>4)<<3)+j, n=nt*16+(lane&15);
    v = pgw[((size_t)ly*512+k)*512+n];
  } else if (t < OFF_WH) {                            // [512][512] fcw
    int q=(int)(t-OFF_WC); int ly=q/SZ_WC; int qq=q%SZ_WC;
    int j=qq&7, lane=(qq>>3)&63, tile=qq>>9, kt=tile&15, nt=tile>>4;
    int k=kt*32+((lane>>4)<<3)+j, n=nt*16+(lane&15);
    v = fcw[((size_t)ly*512+k)*512+n];
  } else if (t < OFF_WH2) {                           // [512][192] heads hidden
    int qq=(int)(t-OFF_WH);
    int j=qq&7, lane=(qq>>3)&63, tile=qq>>9, kt=tile&15, nt=tile>>4;
    int k=kt*32+((lane>>4)<<3)+j, n=nt*16+(lane&15);
    v = (n<64) ? nhw1[(size_t)k*64+n] : (n<128) ? dhw1[(size_t)k*64+(n-64)] : wtw1[(size_t)k*64+(n-128)];
  } else {                                            // [128][256] blockdiag(nhw2,dhw2), K32=4
    int qq=(int)(t-OFF_WH2);
    int j=qq&7, lane=(qq>>3)&63, tile=qq>>9, kt=tile&3, nt=tile>>2;
    int k=kt*32+((lane>>4)<<3)+j, n=nt*16+(lane&15);
    if (k<64) v = (n<128) ? nhw2[(size_t)k*128+n] : 0.f;
    else      v = (n>=128)? dhw2[(size_t)(k-64)*128+(n-128)] : 0.f;
  }
  ws[t] = f2b(v);
}

// ---------------- fused network ----------------
// 16 waves/block, 1 block/CU (LDS-bound) = 4 waves/EU; launch_bounds(1024,4)
// caps VGPR at 128. CRITICAL (rule #20): every local array index must be
// compile-time constant — the p-loops over {0,1} MUST be fully unrolled, else
// pk[p] becomes a scratch alloca (~200MB of HBM scratch traffic, R4-R7 bug).
__global__ __launch_bounds__(1024, 4) void pan_main(
  const float* __restrict__ x,
  const float* __restrict__ pbb,  const float* __restrict__ pab1,
  const float* __restrict__ paw2, const float* __restrict__ pab2,
  const float* __restrict__ pib1, const float* __restrict__ piw2,
  const float* __restrict__ pib2, const float* __restrict__ pfb,
  const float* __restrict__ pgb,  const float* __restrict__ fcb,
  const float* __restrict__ bng,  const float* __restrict__ bnb,
  const float* __restrict__ bnm,  const float* __restrict__ bnv,
  const float* __restrict__ nhb1, const float* __restrict__ nhb2,
  const float* __restrict__ dhb1, const float* __restrict__ dhb2,
  const float* __restrict__ wtb1, const float* __restrict__ wtw2,
  const float* __restrict__ wtb2,
  const short* __restrict__ ws, float* __restrict__ out)
{
  __shared__ __align__(16) char lds[163840];
  char* sH = lds;            // [128][512] bf16, row stride 1024B, byte ^= (row&7)<<4
  char* sU = lds + 131072;   // 32KB union:
                             //  phase A: sT bf16 [128][80] @0 (20480) | ci f32 [128] @20480 | cwci bf16 [128][32] @20992
                             //  phase B: sW bf16 [128][128] swizzled @0 (32768)
                             // heads h1 [128][192] bf16 stride 384 swizzled: stored at lds@0 (sH dead by then)

  const int tid  = threadIdx.x;
  const int wave = tid >> 6;
  const int l    = tid & 63;
  const int lr   = l & 15;
  const int lb   = l >> 4;
  const int swzA = (lr & 7) << 4;
  const size_t row0 = (size_t)blockIdx.x * 128;

  // ---- load x tile -> sH (bf16, swizzled)
  #pragma unroll 2
  for (int c = tid; c < 8192; c += 1024) {
    int row = c >> 6, k0 = (c & 63) << 3;
    const float4* s0 = (const float4*)(x + (row0 + row)*512 + k0);
    float4 f0 = s0[0], f1 = s0[1];
    bf16x8 p;
    p[0]=f2b(f0.x); p[1]=f2b(f0.y); p[2]=f2b(f0.z); p[3]=f2b(f0.w);
    p[4]=f2b(f1.x); p[5]=f2b(f1.y); p[6]=f2b(f1.z); p[7]=f2b(f1.w);
    *(bf16x8*)(sH + row*1024 + ((k0*2) ^ ((row&7)<<4))) = p;
  }
  __syncthreads();

  auto ldA = [&](int rt, int kt) -> bf16x8 {
    int row = rt*16 + lr;
    return *(const bf16x8*)(sH + row*1024 + ((kt*64 + lb*16) ^ swzA));
  };
  auto ldB = [&](const short* W, int K32, int nt, int kt) -> bf16x8 {
    return *(const bf16x8*)(W + (((size_t)(nt*K32 + kt))*64 + l)*8);
  };
  auto ldH = [&](int row, int col) -> float {   // scalar bf16 h read (residual term)
    return b2f(*(const short*)(sH + row*1024 + ((col*2) ^ ((row&7)<<4))));
  };
  const f32x4 FZ = {0.f,0.f,0.f,0.f};

  // ================= PAN layers =================
  for (int ly = 0; ly < 3; ++ly) {
    // --- t_all = relu(h @ [paw1|piw1] + b) -> sT  (N=80: 5 col-tiles x 2 row-halves)
    if (wave < 10) {
      const short* W = ws + OFF_WT + (size_t)ly*SZ_WT;
      const int nt = wave % 5, rh = wave / 5;
      f32x4 acc[4];
      #pragma unroll
      for (int rt=0;rt<4;++rt) acc[rt] = FZ;
      #pragma unroll 2
      for (int kt=0;kt<16;++kt) {
        bf16x8 b = ldB(W,16,nt,kt);
        #pragma unroll
        for (int rt=0;rt<4;++rt) acc[rt] = MFMA(ldA(rh*4+rt,kt), b, acc[rt]);
      }
      const int col = nt*16 + lr;
      const float bias = (col<64) ? pab1[ly*64+col] : pib1[ly*16+(col-64)];
      #pragma unroll
      for (int rt=0;rt<4;++rt)
        #pragma unroll
        for (int jj=0;jj<4;++jj) {
          int row = rh*64 + rt*16 + lb*4 + jj;
          *(short*)(sU + row*160 + col*2) = f2b(fmaxf(acc[rt][jj]+bias, 0.f));
        }
    }
    __syncthreads();
    // --- ci = sigmoid(t2 @ piw2 + b)  (VALU, threads 0..127, vectorized reads)
    if (tid < 128) {
      float s = pib2[ly];
      bf16x8 t0 = *(const bf16x8*)(sU + tid*160 + 128);
      bf16x8 t1 = *(const bf16x8*)(sU + tid*160 + 144);
      #pragma unroll
      for (int i=0;i<8;++i) {
        s += b2f(t0[i]) * piw2[ly*16+i];
        s += b2f(t1[i]) * piw2[ly*16+8+i];
      }
      *(float*)(sU + 20480 + tid*4) = sigm(s);
    }
    __syncthreads();
    // --- cwci = sigmoid(t1 @ paw2 + b) * ci  (all 1024 thr, 4 outputs/thread)
    {
      const int r = tid>>3, j0 = (tid&7)<<2;
      float a4[4];
      #pragma unroll
      for (int i=0;i<4;++i) a4[i] = pab2[ly*32 + j0 + i];
      #pragma unroll 2
      for (int k8=0;k8<8;++k8) {
        bf16x8 tv8 = *(const bf16x8*)(sU + r*160 + k8*16);
        #pragma unroll
        for (int i8=0;i8<8;++i8) {
          float tv = b2f(tv8[i8]);
          float4 wr = *(const float4*)(paw2 + ((size_t)ly*64 + k8*8+i8)*32 + j0);
          a4[0]=fmaf(tv,wr.x,a4[0]); a4[1]=fmaf(tv,wr.y,a4[1]);
          a4[2]=fmaf(tv,wr.z,a4[2]); a4[3]=fmaf(tv,wr.w,a4[3]);
        }
      }
      const float civ = *(const float*)(sU + 20480 + r*4);
      #pragma unroll
      for (int i=0;i<4;++i)
        *(short*)(sU + 20992 + (r*32 + j0 + i)*2) = f2b(sigm(a4[i]) * civ);
    }
    __syncthreads();
    // --- feats = relu(h @ pbw + b); weighted = feats * cwci  (N=96: 6x2 tiles)
    unsigned wpk[4][2];
    if (wave < 12) {
      const short* W = ws + OFF_WB + (size_t)ly*SZ_WB;
      const int nt = wave % 6, rh = wave / 6;
      f32x4 acc[4];
      #pragma unroll
      for (int rt=0;rt<4;++rt) acc[rt] = FZ;
      #pragma unroll 2
      for (int kt=0;kt<16;++kt) {
        bf16x8 b = ldB(W,16,nt,kt);
        #pragma unroll
        for (int rt=0;rt<4;++rt) acc[rt] = MFMA(ldA(rh*4+rt,kt), b, acc[rt]);
      }
      const int col = nt*16 + lr;
      const float bias = pbb[ly*96 + col];
      #pragma unroll
      for (int rt=0;rt<4;++rt) {
        float w4[4];
        #pragma unroll
        for (int jj=0;jj<4;++jj) {
          int row = rh*64 + rt*16 + lb*4 + jj;
          float cc = b2f(*(const short*)(sU + 20992 + (row*32 + (col&31))*2));
          w4[jj] = fmaxf(acc[rt][jj]+bias, 0.f) * cc;
        }
        wpk[rt][0] = pk2(w4[0], w4[1]);
        wpk[rt][1] = pk2(w4[2], w4[3]);
      }
    }
    __syncthreads();           // all phase-A reads of sU done
    if (wave < 12) {           // weighted -> sW (swizzled, stride 256B)
      const int nt = wave % 6, rh = wave / 6;
      const int col = nt*16 + lr;
      #pragma unroll
      for (int rt=0;rt<4;++rt)
        #pragma unroll
        for (int p=0;p<2;++p) {
          int r0 = rh*64 + rt*16 + lb*4 + p*2;
          unsigned v = wpk[rt][p];
          *(short*)(sU + r0*256     + ((col*2) ^ ((r0    &7)<<4))) = (short)(v & 0xffff);
          *(short*)(sU + (r0+1)*256 + ((col*2) ^ (((r0+1)&7)<<4))) = (short)(v >> 16);
        }
    }
    __syncthreads();
    // --- gate = sigmoid(h @ pgw + b); h' = weighted @ pfw + pfb + gate*h
    //     2 single-col passes/wave, p-loop FULLY UNROLLED (static pk indices).
    unsigned pk[2][8][2];
    {
      const short* Wg = ws + OFF_WG + (size_t)ly*SZ_WG;
      const short* Wf = ws + OFF_WF + (size_t)ly*SZ_WF;
      #pragma unroll
      for (int p=0; p<2; ++p) {
        const int c = wave*2 + p;
        f32x4 acc[8];
        #pragma unroll
        for (int rt=0;rt<8;++rt) acc[rt] = FZ;
        #pragma unroll 2
        for (int kt=0;kt<16;++kt) {
          bf16x8 b = ldB(Wg,16, c, kt);
          #pragma unroll
          for (int rt=0;rt<8;++rt) acc[rt] = MFMA(ldA(rt,kt), b, acc[rt]);
        }
        const int col = c*16 + lr;
        const float gb = pgb[ly*512+col];
        const float fb = pfb[ly*512+col];
        #pragma unroll
        for (int rt=0;rt<8;++rt)
          #pragma unroll
          for (int jj=0;jj<4;++jj) {
            int row = rt*16 + lb*4 + jj;
            acc[rt][jj] = sigm(acc[rt][jj]+gb)*ldH(row,col) + fb;
          }
        #pragma unroll 1
        for (int kt=0;kt<3;++kt) {   // fused accumulate, K=96, A from sW
          bf16x8 b = ldB(Wf,3, c, kt);
          #pragma unroll
          for (int rt=0;rt<8;++rt) {
            int row = rt*16 + lr;
            bf16x8 a = *(const bf16x8*)(sU + row*256 + ((kt*64 + lb*16) ^ swzA));
            acc[rt] = MFMA(a,b,acc[rt]);
          }
        }
        #pragma unroll
        for (int rt=0;rt<8;++rt) {
          pk[p][rt][0] = pk2(acc[rt][0], acc[rt][1]);
          pk[p][rt][1] = pk2(acc[rt][2], acc[rt][3]);
        }
      }
    }
    __syncthreads();           // all reads of old h / sW complete
    #pragma unroll
    for (int p=0;p<2;++p) {    // publish h' bf16
      const int col = (wave*2+p)*16 + lr;
      #pragma unroll
      for (int rt=0;rt<8;++rt)
        #pragma unroll
        for (int q=0;q<2;++q) {
          int r0 = rt*16 + lb*4 + q*2;
          unsigned v = pk[p][rt][q];
          *(short*)(sH + r0*1024     + ((col*2) ^ ((r0    &7)<<4))) = (short)(v & 0xffff);
          *(short*)(sH + (r0+1)*1024 + ((col*2) ^ (((r0+1)&7)<<4))) = (short)(v >> 16);
        }
    }
    __syncthreads();
  }

  // ================= FC + BN(eval) + ReLU  x3 =================
  for (int fi=0; fi<3; ++fi) {
    const short* W = ws + OFF_WC + (size_t)fi*SZ_WC;
    unsigned pk[2][8][2];
    #pragma unroll
    for (int p=0; p<2; ++p) {
      const int c = wave*2 + p;
      f32x4 acc[8];
      #pragma unroll
      for (int rt=0;rt<8;++rt) acc[rt] = FZ;
      #pragma unroll 2
      for (int kt=0;kt<16;++kt) {
        bf16x8 b = ldB(W,16, c, kt);
        #pragma unroll
        for (int rt=0;rt<8;++rt) acc[rt] = MFMA(ldA(rt,kt), b, acc[rt]);
      }
      const int col = c*16 + lr;
      const float sc = bng[fi*512+col] * rsqrtf(bnv[fi*512+col] + 1e-5f);
      const float of = bnb[fi*512+col] - bnm[fi*512+col]*sc;
      const float bb = fcb[fi*512+col];
      #pragma unroll
      for (int rt=0;rt<8;++rt) {
        float z0 = fmaxf((acc[rt][0] + bb)*sc + of, 0.f);
        float z1 = fmaxf((acc[rt][1] + bb)*sc + of, 0.f);
        float z2 = fmaxf((acc[rt][2] + bb)*sc + of, 0.f);
        float z3 = fmaxf((acc[rt][3] + bb)*sc + of, 0.f);
        pk[p][rt][0] = pk2(z0, z1);
        pk[p][rt][1] = pk2(z2, z3);
      }
    }
    __syncthreads();
    #pragma unroll
    for (int p=0;p<2;++p) {
      const int col = (wave*2+p)*16 + lr;
      #pragma unroll
      for (int rt=0;rt<8;++rt)
        #pragma unroll
        for (int q=0;q<2;++q) {
          int r0 = rt*16 + lb*4 + q*2;
          unsigned v = pk[p][rt][q];
          *(short*)(sH + r0*1024     + ((col*2) ^ ((r0    &7)<<4))) = (short)(v & 0xffff);
          *(short*)(sH + (r0+1)*1024 + ((col*2) ^ (((r0+1)&7)<<4))) = (short)(v >> 16);
        }
    }
    __syncthreads();
  }

  // ================= heads =================
  // h1 = relu(h @ [nhw1|dhw1|wtw1] + b): N=192, 12 waves, full rows.
  // Result parked in regs (packed bf16), then written to lds@0 (sH dead) stride 384.
  unsigned hk[8][2];
  if (wave < 12) {
    const short* W = ws + OFF_WH;
    f32x4 acc[8];
    #pragma unroll
    for (int rt=0;rt<8;++rt) acc[rt] = FZ;
    #pragma unroll 2
    for (int kt=0;kt<16;++kt) {
      bf16x8 b = ldB(W,16,wave,kt);
      #pragma unroll
      for (int rt=0;rt<8;++rt) acc[rt] = MFMA(ldA(rt,kt), b, acc[rt]);
    }
    const int col = wave*16 + lr;
    const float bias = (col<64) ? nhb1[col] : (col<128) ? dhb1[col-64] : wtb1[col-128];
    #pragma unroll
    for (int rt=0;rt<8;++rt) {
      hk[rt][0] = pk2(fmaxf(acc[rt][0]+bias,0.f), fmaxf(acc[rt][1]+bias,0.f));
      hk[rt][1] = pk2(fmaxf(acc[rt][2]+bias,0.f), fmaxf(acc[rt][3]+bias,0.f));
    }
  }
  __syncthreads();             // sH reads done
  if (wave < 12) {             // h1 -> lds@0, [128][192] stride 384B, swizzled
    const int col = wave*16 + lr;
    #pragma unroll
    for (int rt=0;rt<8;++rt)
      #pragma unroll
      for (int q=0;q<2;++q) {
        int r0 = rt*16 + lb*4 + q*2;
        unsigned v = hk[rt][q];
        *(short*)(lds + r0*384     + ((col*2) ^ ((r0    &7)<<4))) = (short)(v & 0xffff);
        *(short*)(lds + (r0+1)*384 + ((col*2) ^ (((r0+1)&7)<<4))) = (short)(v >> 16);
      }
  }
  __syncthreads();
  { // logits = h1[:, :128] @ blockdiag(nhw2,dhw2): 16 waves x 1 col-tile, K=128
    const short* W2 = ws + OFF_WH2;
    f32x4 acc[8];
    #pragma unroll
    for (int rt=0;rt<8;++rt) acc[rt] = FZ;
    #pragma unroll 2
    for (int kt=0;kt<4;++kt) {
      bf16x8 b = ldB(W2,4, wave, kt);
      #pragma unroll
      for (int rt=0;rt<8;++rt) {
        int row = rt*16 + lr;
        bf16x8 a = *(const bf16x8*)(lds + row*384 + ((kt*64 + lb*16) ^ swzA));
        acc[rt] = MFMA(a,b,acc[rt]);
      }
    }
    const int col2 = wave*16 + lr;
    const bool isn = col2 < 128;
    const int cc = col2 & 127;
    const float bias = isn ? nhb2[cc] : dhb2[cc];
    const size_t obase = isn ? (size_t)0 : (size_t)4194304;
    #pragma unroll
    for (int rt=0;rt<8;++rt)
      #pragma unroll
      for (int jj=0;jj<4;++jj) {
        int row = rt*16 + lb*4 + jj;
        size_t rg = row0 + row;
        float2 caps = *(const float2*)(x + rg*512 + 508);   // (s_nurse_max, s_doctor_max)
        int cap = (int)(isn ? caps.x : caps.y);
        float v = acc[rt][jj] + bias;
        out[obase + rg*128 + cc] = (cc <= cap) ? v : -1e9f;
      }
  }
  // wait_time = h1[:, 128:192] @ wtw2 + b (read-only on h1; no barrier needed)
  if (tid < 128) {
    float s = wtb2[0];
    #pragma unroll 2
    for (int k8=0;k8<8;++k8) {
      bf16x8 hv = *(const bf16x8*)(lds + tid*384 + ((256 + k8*16) ^ ((tid&7)<<4)));
      #pragma unroll
      for (int i=0;i<8;++i) s += b2f(hv[i]) * wtw2[k8*8+i];
    }
    out[(size_t)8388608 + row0 + tid] = s;
  }
}

extern "C" void kernel_launch(void* const* d_in, const int* in_sizes, int n_in,
                              void* d_out, int out_size, void* d_ws, size_t ws_size,
                              hipStream_t stream) {
  const float* x    = (const float*)d_in[0];
  const float* pbw  = (const float*)d_in[1];
  const float* pbb  = (const float*)d_in[2];
  const float* paw1 = (const float*)d_in[3];
  const float* pab1 = (const float*)d_in[4];
  const float* paw2 = (const float*)d_in[5];
  const float* pab2 = (const float*)d_in[6];
  const float* piw1 = (const float*)d_in[7];
  const float* pib1 = (const float*)d_in[8];
  const float* piw2 = (const float*)d_in[9];
  const float* pib2 = (const float*)d_in[10];
  const float* pfw  = (const float*)d_in[11];
  const float* pfb  = (const float*)d_in[12];
  const float* pgw  = (const float*)d_in[13];
  const float* pgb  = (const float*)d_in[14];
  const float* fcw  = (const float*)d_in[15];
  const float* fcb  = (const float*)d_in[16];
  const float* bng  = (const float*)d_in[17];
  const float* bnb  = (const float*)d_in[18];
  const float* bnm  = (const float*)d_in[19];
  const float* bnv  = (const float*)d_in[20];
  const float* nhw1 = (const float*)d_in[21];
  const float* nhb1 = (const float*)d_in[22];
  const float* nhw2 = (const float*)d_in[23];
  const float* nhb2 = (const float*)d_in[24];
  const float* dhw1 = (const float*)d_in[25];
  const float* dhb1 = (const float*)d_in[26];
  const float* dhw2 = (const float*)d_in[27];
  const float* dhb2 = (const float*)d_in[28];
  const float* wtw1 = (const float*)d_in[29];
  const float* wtb1 = (const float*)d_in[30];
  const float* wtw2 = (const float*)d_in[31];
  const float* wtb2 = (const float*)d_in[32];
  short* ws  = (short*)d_ws;
  float* out = (float*)d_out;

  prep_weights<<<(int)((WS_TOTAL + 255)/256), 256, 0, stream>>>(
      pbw, paw1, piw1, pfw, pgw, fcw, nhw1, nhw2, dhw1, dhw2, wtw1, ws);
  pan_main<<<256, 1024, 0, stream>>>(
      x, pbb, pab1, paw2, pab2, pib1, piw2, pib2, pfb, pgb, fcb,
      bng, bnb, bnm, bnv, nhb1, nhb2, dhb1, dhb2, wtb1, wtw2, wtb2, ws, out);
}

// Round 9
// 330.108 us; speedup vs baseline: 1.1313x; 1.1313x over previous
//
#include <hip/hip_runtime.h>

#define DI __device__ __forceinline__

typedef short bf16x8 __attribute__((ext_vector_type(8)));
typedef float f32x4  __attribute__((ext_vector_type(4)));

#define MFMA(a,b,c) __builtin_amdgcn_mfma_f32_16x16x32_bf16(a,b,c,0,0,0)

constexpr int    SZ_WT = 512*80;
constexpr int    SZ_WB = 512*96;
constexpr int    SZ_WF = 96*512;
constexpr int    SZ_WG = 512*512;
constexpr int    SZ_WC = 512*512;
constexpr size_t OFF_WT  = 0;
constexpr size_t OFF_WB  = OFF_WT + 3*(size_t)SZ_WT;     // 122880
constexpr size_t OFF_WF  = OFF_WB + 3*(size_t)SZ_WB;     // 270336
constexpr size_t OFF_WG  = OFF_WF + 3*(size_t)SZ_WF;     // 417792
constexpr size_t OFF_WC  = OFF_WG + 3*(size_t)SZ_WG;     // 1204224
constexpr size_t OFF_WH  = OFF_WC + 3*(size_t)SZ_WC;     // 1990656  [512][192] nhw1|dhw1|wtw1
constexpr size_t OFF_WH2 = OFF_WH + (size_t)512*192;     // 2088960  [128][256] blockdiag(nhw2,dhw2)
constexpr size_t WS_TOTAL= OFF_WH2 + (size_t)128*256;    // 2121728 bf16 elems

DI short f2b(float f){ unsigned u; __builtin_memcpy(&u,&f,4); u += 0x7fffu + ((u>>16)&1u); return (short)(u>>16); }
DI float b2f(short s){ unsigned u = ((unsigned)(unsigned short)s)<<16; float f; __builtin_memcpy(&f,&u,4); return f; }
DI float sigm(float x){ return 1.f/(1.f+__expf(-x)); }
DI unsigned pk2(float a, float b){
  return (unsigned)(unsigned short)f2b(a) | ((unsigned)(unsigned short)f2b(b) << 16);
}

// ---------------- weight prepass: fp32 -> bf16 MFMA-B-fragment layout ----------------
// frag element t = ((nt*K32 + kt)*64 + lane)*8 + j  <->  W[kt*32 + (lane>>4)*8 + j][nt*16 + (lane&15)]
__global__ __launch_bounds__(256) void prep_weights(
    const float* __restrict__ pbw,  const float* __restrict__ paw1,
    const float* __restrict__ piw1, const float* __restrict__ pfw,
    const float* __restrict__ pgw,  const float* __restrict__ fcw,
    const float* __restrict__ nhw1, const float* __restrict__ nhw2,
    const float* __restrict__ dhw1, const float* __restrict__ dhw2,
    const float* __restrict__ wtw1, short* __restrict__ ws)
{
  size_t t = (size_t)blockIdx.x*256 + threadIdx.x;
  if (t >= WS_TOTAL) return;
  float v = 0.f;
  if (t < OFF_WB) {                                   // [512][80] = paw1 | piw1, K32=16
    int q=(int)t; int ly=q/SZ_WT; int qq=q%SZ_WT;
    int j=qq&7, lane=(qq>>3)&63, tile=qq>>9, kt=tile&15, nt=tile>>4;
    int k=kt*32+((lane>>4)<<3)+j, n=nt*16+(lane&15);
    v = (n<64) ? paw1[((size_t)ly*512+k)*64+n] : piw1[((size_t)ly*512+k)*16+(n-64)];
  } else if (t < OFF_WF) {                            // [512][96] pbw flat (c=k*32+j), K32=16
    int q=(int)(t-OFF_WB); int ly=q/SZ_WB; int qq=q%SZ_WB;
    int j=qq&7, lane=(qq>>3)&63, tile=qq>>9, kt=tile&15, nt=tile>>4;
    int k=kt*32+((lane>>4)<<3)+j, c=nt*16+(lane&15);
    v = pbw[(((size_t)ly*3+(c>>5))*512+k)*32+(c&31)];
  } else if (t < OFF_WG) {                            // [96][512] pfw, K32=3
    int q=(int)(t-OFF_WF); int ly=q/SZ_WF; int qq=q%SZ_WF;
    int j=qq&7, lane=(qq>>3)&63, tile=qq>>9, kt=tile%3, nt=tile/3;
    int k=kt*32+((lane>>4)<<3)+j, n=nt*16+(lane&15);
    v = pfw[((size_t)ly*96+k)*512+n];
  } else if (t < OFF_WC) {                            // [512][512] pgw
    int q=(int)(t-OFF_WG); int ly=q/SZ_WG; int qq=q%SZ_WG;
    int j=qq&7, lane=(qq>>3)&63, tile=qq>>9, kt=tile&15, nt=tile>>4;
    int k=kt*32+((lane>>4)<<3)+j, n=nt*16+(lane&15);
    v = pgw[((size_t)ly*512+k)*512+n];
  } else if (t < OFF_WH) {                            // [512][512] fcw
    int q=(int)(t-OFF_WC); int ly=q/SZ_WC; int qq=q%SZ_WC;
    int j=qq&7, lane=(qq>>3)&63, tile=qq>>9, kt=tile&15, nt=tile>>4;
    int k=kt*32+((lane>>4)<<3)+j, n=nt*16+(lane&15);
    v = fcw[((size_t)ly*512+k)*512+n];
  } else if (t < OFF_WH2) {                           // [512][192] heads hidden
    int qq=(int)(t-OFF_WH);
    int j=qq&7, lane=(qq>>3)&63, tile=qq>>9, kt=tile&15, nt=tile>>4;
    int k=kt*32+((lane>>4)<<3)+j, n=nt*16+(lane&15);
    v = (n<64) ? nhw1[(size_t)k*64+n] : (n<128) ? dhw1[(size_t)k*64+(n-64)] : wtw1[(size_t)k*64+(n-128)];
  } else {                                            // [128][256] blockdiag(nhw2,dhw2), K32=4
    int qq=(int)(t-OFF_WH2);
    int j=qq&7, lane=(qq>>3)&63, tile=qq>>9, kt=tile&3, nt=tile>>2;
    int k=kt*32+((lane>>4)<<3)+j, n=nt*16+(lane&15);
    if (k<64) v = (n<128) ? nhw2[(size_t)k*128+n] : 0.f;
    else      v = (n>=128)? dhw2[(size_t)(k-64)*128+(n-128)] : 0.f;
  }
  ws[t] = f2b(v);
}

// ---------------- fused network ----------------
// 64 rows/block, 512 threads (8 waves), LDS=80KB -> 2 blocks/CU (16 waves/CU,
// 4 waves/SIMD). Empirical RA cap is 65536/blockDim VGPRs: B=512 -> 128, which
// fits this tiling's ~90-reg live state spill-free (B=1024 capped at 64 and
// spilled ~200MB; attributes never moved the cap). All local arrays indexed
// with compile-time constants (rule #20).
__global__ __launch_bounds__(512, 4) void pan_main(
  const float* __restrict__ x,
  const float* __restrict__ pbb,  const float* __restrict__ pab1,
  const float* __restrict__ paw2, const float* __restrict__ pab2,
  const float* __restrict__ pib1, const float* __restrict__ piw2,
  const float* __restrict__ pib2, const float* __restrict__ pfb,
  const float* __restrict__ pgb,  const float* __restrict__ fcb,
  const float* __restrict__ bng,  const float* __restrict__ bnb,
  const float* __restrict__ bnm,  const float* __restrict__ bnv,
  const float* __restrict__ nhb1, const float* __restrict__ nhb2,
  const float* __restrict__ dhb1, const float* __restrict__ dhb2,
  const float* __restrict__ wtb1, const float* __restrict__ wtw2,
  const float* __restrict__ wtb2,
  const short* __restrict__ ws, float* __restrict__ out)
{
  __shared__ __align__(16) char lds[81920];
  char* sH = lds;            // [64][512] bf16, row stride 1024B, byte ^= (row&7)<<4
  char* sU = lds + 65536;    // 16KB union:
                             //  phase A: sT bf16 [64][80] @0 (10240) | ci f32 [64] @10240 | cwci bf16 [64][32] @10496
                             //  phase B: sW bf16 [64][128] swizzled @0 (16384)
                             // heads h1 [64][192] bf16 stride 384 swizzled at lds@0 (sH dead by then)

  const int tid  = threadIdx.x;
  const int wave = tid >> 6;
  const int l    = tid & 63;
  const int lr   = l & 15;
  const int lb   = l >> 4;
  const int swzA = (lr & 7) << 4;
  const size_t row0 = (size_t)blockIdx.x * 64;

  // ---- load x tile -> sH (bf16, swizzled)
  #pragma unroll 2
  for (int c = tid; c < 4096; c += 512) {
    int row = c >> 6, k0 = (c & 63) << 3;
    const float4* s0 = (const float4*)(x + (row0 + row)*512 + k0);
    float4 f0 = s0[0], f1 = s0[1];
    bf16x8 p;
    p[0]=f2b(f0.x); p[1]=f2b(f0.y); p[2]=f2b(f0.z); p[3]=f2b(f0.w);
    p[4]=f2b(f1.x); p[5]=f2b(f1.y); p[6]=f2b(f1.z); p[7]=f2b(f1.w);
    *(bf16x8*)(sH + row*1024 + ((k0*2) ^ ((row&7)<<4))) = p;
  }
  __syncthreads();

  auto ldA = [&](int rt, int kt) -> bf16x8 {
    int row = rt*16 + lr;
    return *(const bf16x8*)(sH + row*1024 + ((kt*64 + lb*16) ^ swzA));
  };
  auto ldB = [&](const short* W, int K32, int nt, int kt) -> bf16x8 {
    return *(const bf16x8*)(W + (((size_t)(nt*K32 + kt))*64 + l)*8);
  };
  auto ldH = [&](int row, int col) -> float {   // scalar bf16 h read (residual term)
    return b2f(*(const short*)(sH + row*1024 + ((col*2) ^ ((row&7)<<4))));
  };
  const f32x4 FZ = {0.f,0.f,0.f,0.f};

  // ================= PAN layers =================
  for (int ly = 0; ly < 3; ++ly) {
    // --- t_all = relu(h @ [paw1|piw1] + b) -> sT  (N=80: waves 0..4)
    if (wave < 5) {
      const short* W = ws + OFF_WT + (size_t)ly*SZ_WT;
      f32x4 acc[4];
      #pragma unroll
      for (int rt=0;rt<4;++rt) acc[rt] = FZ;
      #pragma unroll 2
      for (int kt=0;kt<16;++kt) {
        bf16x8 b = ldB(W,16,wave,kt);
        #pragma unroll
        for (int rt=0;rt<4;++rt) acc[rt] = MFMA(ldA(rt,kt), b, acc[rt]);
      }
      const int col = wave*16 + lr;
      const float bias = (col<64) ? pab1[ly*64+col] : pib1[ly*16+(col-64)];
      #pragma unroll
      for (int rt=0;rt<4;++rt)
        #pragma unroll
        for (int jj=0;jj<4;++jj) {
          int row = rt*16 + lb*4 + jj;
          *(short*)(sU + row*160 + col*2) = f2b(fmaxf(acc[rt][jj]+bias, 0.f));
        }
    }
    __syncthreads();
    // --- ci = sigmoid(t2 @ piw2 + b)  (threads 0..63, vectorized reads)
    if (tid < 64) {
      float s = pib2[ly];
      bf16x8 t0 = *(const bf16x8*)(sU + tid*160 + 128);
      bf16x8 t1 = *(const bf16x8*)(sU + tid*160 + 144);
      #pragma unroll
      for (int i=0;i<8;++i) {
        s += b2f(t0[i]) * piw2[ly*16+i];
        s += b2f(t1[i]) * piw2[ly*16+8+i];
      }
      *(float*)(sU + 10240 + tid*4) = sigm(s);
    }
    __syncthreads();
    // --- cwci = sigmoid(t1 @ paw2 + b) * ci  (all 512 thr, 4 outputs/thread)
    {
      const int r = tid>>3, j0 = (tid&7)<<2;
      float a4[4];
      #pragma unroll
      for (int i=0;i<4;++i) a4[i] = pab2[ly*32 + j0 + i];
      #pragma unroll 2
      for (int k8=0;k8<8;++k8) {
        bf16x8 tv8 = *(const bf16x8*)(sU + r*160 + k8*16);
        #pragma unroll
        for (int i8=0;i8<8;++i8) {
          float tv = b2f(tv8[i8]);
          float4 wr = *(const float4*)(paw2 + ((size_t)ly*64 + k8*8+i8)*32 + j0);
          a4[0]=fmaf(tv,wr.x,a4[0]); a4[1]=fmaf(tv,wr.y,a4[1]);
          a4[2]=fmaf(tv,wr.z,a4[2]); a4[3]=fmaf(tv,wr.w,a4[3]);
        }
      }
      const float civ = *(const float*)(sU + 10240 + r*4);
      #pragma unroll
      for (int i=0;i<4;++i)
        *(short*)(sU + 10496 + (r*32 + j0 + i)*2) = f2b(sigm(a4[i]) * civ);
    }
    __syncthreads();
    // --- feats = relu(h @ pbw + b); weighted = feats * cwci  (N=96: waves 0..5)
    unsigned wpk[4][2];
    if (wave < 6) {
      const short* W = ws + OFF_WB + (size_t)ly*SZ_WB;
      f32x4 acc[4];
      #pragma unroll
      for (int rt=0;rt<4;++rt) acc[rt] = FZ;
      #pragma unroll 2
      for (int kt=0;kt<16;++kt) {
        bf16x8 b = ldB(W,16,wave,kt);
        #pragma unroll
        for (int rt=0;rt<4;++rt) acc[rt] = MFMA(ldA(rt,kt), b, acc[rt]);
      }
      const int col = wave*16 + lr;
      const float bias = pbb[ly*96 + col];
      #pragma unroll
      for (int rt=0;rt<4;++rt) {
        float w4[4];
        #pragma unroll
        for (int jj=0;jj<4;++jj) {
          int row = rt*16 + lb*4 + jj;
          float cc = b2f(*(const short*)(sU + 10496 + (row*32 + (col&31))*2));
          w4[jj] = fmaxf(acc[rt][jj]+bias, 0.f) * cc;
        }
        wpk[rt][0] = pk2(w4[0], w4[1]);
        wpk[rt][1] = pk2(w4[2], w4[3]);
      }
    }
    __syncthreads();           // all phase-A reads of sU done
    if (wave < 6) {            // weighted -> sW (swizzled, stride 256B)
      const int col = wave*16 + lr;
      #pragma unroll
      for (int rt=0;rt<4;++rt)
        #pragma unroll
        for (int p=0;p<2;++p) {
          int r0 = rt*16 + lb*4 + p*2;
          unsigned v = wpk[rt][p];
          *(short*)(sU + r0*256     + ((col*2) ^ ((r0    &7)<<4))) = (short)(v & 0xffff);
          *(short*)(sU + (r0+1)*256 + ((col*2) ^ (((r0+1)&7)<<4))) = (short)(v >> 16);
        }
    }
    __syncthreads();
    // --- gate = sigmoid(h @ pgw + b); h' = weighted @ pfw + pfb + gate*h
    //     4 cols/wave, 2 fully-unrolled passes of 2 cols. pk indices static.
    unsigned pk[4][4][2];
    {
      const short* Wg = ws + OFF_WG + (size_t)ly*SZ_WG;
      const short* Wf = ws + OFF_WF + (size_t)ly*SZ_WF;
      #pragma unroll
      for (int p=0; p<2; ++p) {
        f32x4 acc[4][2];
        #pragma unroll
        for (int rt=0;rt<4;++rt) { acc[rt][0]=FZ; acc[rt][1]=FZ; }
        #pragma unroll 2
        for (int kt=0;kt<16;++kt) {
          bf16x8 b0 = ldB(Wg,16, wave*4+p*2+0, kt);
          bf16x8 b1 = ldB(Wg,16, wave*4+p*2+1, kt);
          #pragma unroll
          for (int rt=0;rt<4;++rt) {
            bf16x8 a = ldA(rt,kt);
            acc[rt][0] = MFMA(a,b0,acc[rt][0]);
            acc[rt][1] = MFMA(a,b1,acc[rt][1]);
          }
        }
        #pragma unroll
        for (int c2=0;c2<2;++c2) {
          const int col = (wave*4+p*2+c2)*16 + lr;
          const float gb = pgb[ly*512+col];
          const float fb = pfb[ly*512+col];
          #pragma unroll
          for (int rt=0;rt<4;++rt)
            #pragma unroll
            for (int jj=0;jj<4;++jj) {
              int row = rt*16 + lb*4 + jj;
              acc[rt][c2][jj] = sigm(acc[rt][c2][jj]+gb)*ldH(row,col) + fb;
            }
        }
        #pragma unroll 1
        for (int kt=0;kt<3;++kt) {   // fused accumulate, K=96, A from sW
          bf16x8 b0 = ldB(Wf,3, wave*4+p*2+0, kt);
          bf16x8 b1 = ldB(Wf,3, wave*4+p*2+1, kt);
          #pragma unroll
          for (int rt=0;rt<4;++rt) {
            int row = rt*16 + lr;
            bf16x8 a = *(const bf16x8*)(sU + row*256 + ((kt*64 + lb*16) ^ swzA));
            acc[rt][0] = MFMA(a,b0,acc[rt][0]);
            acc[rt][1] = MFMA(a,b1,acc[rt][1]);
          }
        }
        #pragma unroll
        for (int c2=0;c2<2;++c2)
          #pragma unroll
          for (int rt=0;rt<4;++rt) {
            pk[p*2+c2][rt][0] = pk2(acc[rt][c2][0], acc[rt][c2][1]);
            pk[p*2+c2][rt][1] = pk2(acc[rt][c2][2], acc[rt][c2][3]);
          }
      }
    }
    __syncthreads();           // all reads of old h / sW complete
    #pragma unroll
    for (int ci2=0;ci2<4;++ci2) {   // publish h' bf16
      const int col = (wave*4+ci2)*16 + lr;
      #pragma unroll
      for (int rt=0;rt<4;++rt)
        #pragma unroll
        for (int q=0;q<2;++q) {
          int r0 = rt*16 + lb*4 + q*2;
          unsigned v = pk[ci2][rt][q];
          *(short*)(sH + r0*1024     + ((col*2) ^ ((r0    &7)<<4))) = (short)(v & 0xffff);
          *(short*)(sH + (r0+1)*1024 + ((col*2) ^ (((r0+1)&7)<<4))) = (short)(v >> 16);
        }
    }
    __syncthreads();
  }

  // ================= FC + BN(eval) + ReLU  x3 =================
  for (int fi=0; fi<3; ++fi) {
    const short* W = ws + OFF_WC + (size_t)fi*SZ_WC;
    unsigned pk[4][4][2];
    #pragma unroll
    for (int p=0; p<2; ++p) {
      f32x4 acc[4][2];
      #pragma unroll
      for (int rt=0;rt<4;++rt) { acc[rt][0]=FZ; acc[rt][1]=FZ; }
      #pragma unroll 2
      for (int kt=0;kt<16;++kt) {
        bf16x8 b0 = ldB(W,16, wave*4+p*2+0, kt);
        bf16x8 b1 = ldB(W,16, wave*4+p*2+1, kt);
        #pragma unroll
        for (int rt=0;rt<4;++rt) {
          bf16x8 a = ldA(rt,kt);
          acc[rt][0] = MFMA(a,b0,acc[rt][0]);
          acc[rt][1] = MFMA(a,b1,acc[rt][1]);
        }
      }
      #pragma unroll
      for (int c2=0;c2<2;++c2) {
        const int col = (wave*4+p*2+c2)*16 + lr;
        const float sc = bng[fi*512+col] * rsqrtf(bnv[fi*512+col] + 1e-5f);
        const float of = bnb[fi*512+col] - bnm[fi*512+col]*sc;
        const float bb = fcb[fi*512+col];
        #pragma unroll
        for (int rt=0;rt<4;++rt) {
          float z0 = fmaxf((acc[rt][c2][0] + bb)*sc + of, 0.f);
          float z1 = fmaxf((acc[rt][c2][1] + bb)*sc + of, 0.f);
          float z2 = fmaxf((acc[rt][c2][2] + bb)*sc + of, 0.f);
          float z3 = fmaxf((acc[rt][c2][3] + bb)*sc + of, 0.f);
          pk[p*2+c2][rt][0] = pk2(z0, z1);
          pk[p*2+c2][rt][1] = pk2(z2, z3);
        }
      }
    }
    __syncthreads();
    #pragma unroll
    for (int ci2=0;ci2<4;++ci2) {
      const int col = (wave*4+ci2)*16 + lr;
      #pragma unroll
      for (int rt=0;rt<4;++rt)
        #pragma unroll
        for (int q=0;q<2;++q) {
          int r0 = rt*16 + lb*4 + q*2;
          unsigned v = pk[ci2][rt][q];
          *(short*)(sH + r0*1024     + ((col*2) ^ ((r0    &7)<<4))) = (short)(v & 0xffff);
          *(short*)(sH + (r0+1)*1024 + ((col*2) ^ (((r0+1)&7)<<4))) = (short)(v >> 16);
        }
    }
    __syncthreads();
  }

  // ================= heads =================
  // h1 = relu(h @ [nhw1|dhw1|wtw1] + b): N=192 = 12 tiles; wave does tile
  // `wave` (A) and, for wave<4, tile 8+wave (B). Held in regs across barrier.
  unsigned hkA[4][2], hkB[4][2];
  {
    const short* W = ws + OFF_WH;
    {
      f32x4 acc[4];
      #pragma unroll
      for (int rt=0;rt<4;++rt) acc[rt] = FZ;
      #pragma unroll 2
      for (int kt=0;kt<16;++kt) {
        bf16x8 b = ldB(W,16,wave,kt);
        #pragma unroll
        for (int rt=0;rt<4;++rt) acc[rt] = MFMA(ldA(rt,kt), b, acc[rt]);
      }
      const int col = wave*16 + lr;
      const float bias = (col<64) ? nhb1[col] : dhb1[col-64];
      #pragma unroll
      for (int rt=0;rt<4;++rt) {
        hkA[rt][0] = pk2(fmaxf(acc[rt][0]+bias,0.f), fmaxf(acc[rt][1]+bias,0.f));
        hkA[rt][1] = pk2(fmaxf(acc[rt][2]+bias,0.f), fmaxf(acc[rt][3]+bias,0.f));
      }
    }
    if (wave < 4) {
      f32x4 acc[4];
      #pragma unroll
      for (int rt=0;rt<4;++rt) acc[rt] = FZ;
      #pragma unroll 2
      for (int kt=0;kt<16;++kt) {
        bf16x8 b = ldB(W,16, 8+wave, kt);
        #pragma unroll
        for (int rt=0;rt<4;++rt) acc[rt] = MFMA(ldA(rt,kt), b, acc[rt]);
      }
      const int col = (8+wave)*16 + lr;   // 128..191 -> wait-head hidden
      const float bias = wtb1[col-128];
      #pragma unroll
      for (int rt=0;rt<4;++rt) {
        hkB[rt][0] = pk2(fmaxf(acc[rt][0]+bias,0.f), fmaxf(acc[rt][1]+bias,0.f));
        hkB[rt][1] = pk2(fmaxf(acc[rt][2]+bias,0.f), fmaxf(acc[rt][3]+bias,0.f));
      }
    }
  }
  __syncthreads();             // sH reads done
  {                            // h1 -> lds@0, [64][192] stride 384B, swizzled
    #pragma unroll
    for (int rt=0;rt<4;++rt)
      #pragma unroll
      for (int q=0;q<2;++q) {
        int r0 = rt*16 + lb*4 + q*2;
        int cA = wave*16 + lr;
        unsigned v = hkA[rt][q];
        *(short*)(lds + r0*384     + ((cA*2) ^ ((r0    &7)<<4))) = (short)(v & 0xffff);
        *(short*)(lds + (r0+1)*384 + ((cA*2) ^ (((r0+1)&7)<<4))) = (short)(v >> 16);
      }
    if (wave < 4) {
      #pragma unroll
      for (int rt=0;rt<4;++rt)
        #pragma unroll
        for (int q=0;q<2;++q) {
          int r0 = rt*16 + lb*4 + q*2;
          int cB = (8+wave)*16 + lr;
          unsigned v = hkB[rt][q];
          *(short*)(lds + r0*384     + ((cB*2) ^ ((r0    &7)<<4))) = (short)(v & 0xffff);
          *(short*)(lds + (r0+1)*384 + ((cB*2) ^ (((r0+1)&7)<<4))) = (short)(v >> 16);
        }
    }
  }
  __syncthreads();
  { // logits = h1[:, :128] @ blockdiag(nhw2,dhw2): 16 tiles = 8 waves x 2
    const short* W2 = ws + OFF_WH2;
    #pragma unroll
    for (int p=0;p<2;++p) {
      f32x4 acc[4];
      #pragma unroll
      for (int rt=0;rt<4;++rt) acc[rt] = FZ;
      #pragma unroll 2
      for (int kt=0;kt<4;++kt) {
        bf16x8 b = ldB(W2,4, wave*2+p, kt);
        #pragma unroll
        for (int rt=0;rt<4;++rt) {
          int row = rt*16 + lr;
          bf16x8 a = *(const bf16x8*)(lds + row*384 + ((kt*64 + lb*16) ^ swzA));
          acc[rt] = MFMA(a,b,acc[rt]);
        }
      }
      const int col2 = (wave*2+p)*16 + lr;
      const bool isn = col2 < 128;
      const int cc = col2 & 127;
      const float bias = isn ? nhb2[cc] : dhb2[cc];
      const size_t obase = isn ? (size_t)0 : (size_t)4194304;
      #pragma unroll
      for (int rt=0;rt<4;++rt)
        #pragma unroll
        for (int jj=0;jj<4;++jj) {
          int row = rt*16 + lb*4 + jj;
          size_t rg = row0 + row;
          float2 caps = *(const float2*)(x + rg*512 + 508);   // (s_nurse_max, s_doctor_max)
          int cap = (int)(isn ? caps.x : caps.y);
          float v = acc[rt][jj] + bias;
          out[obase + rg*128 + cc] = (cc <= cap) ? v : -1e9f;
        }
    }
  }
  // wait_time = h1[:, 128:192] @ wtw2 + b (read-only on h1)
  if (tid < 64) {
    float s = wtb2[0];
    #pragma unroll 2
    for (int k8=0;k8<8;++k8) {
      bf16x8 hv = *(const bf16x8*)(lds + tid*384 + ((256 + k8*16) ^ ((tid&7)<<4)));
      #pragma unroll
      for (int i=0;i<8;++i) s += b2f(hv[i]) * wtw2[k8*8+i];
    }
    out[(size_t)8388608 + row0 + tid] = s;
  }
}

extern "C" void kernel_launch(void* const* d_in, const int* in_sizes, int n_in,
                              void* d_out, int out_size, void* d_ws, size_t ws_size,
                              hipStream_t stream) {
  const float* x    = (const float*)d_in[0];
  const float* pbw  = (const float*)d_in[1];
  const float* pbb  = (const float*)d_in[2];
  const float* paw1 = (const float*)d_in[3];
  const float* pab1 = (const float*)d_in[4];
  const float* paw2 = (const float*)d_in[5];
  const float* pab2 = (const float*)d_in[6];
  const float* piw1 = (const float*)d_in[7];
  const float* pib1 = (const float*)d_in[8];
  const float* piw2 = (const float*)d_in[9];
  const float* pib2 = (const float*)d_in[10];
  const float* pfw  = (const float*)d_in[11];
  const float* pfb  = (const float*)d_in[12];
  const float* pgw  = (const float*)d_in[13];
  const float* pgb  = (const float*)d_in[14];
  const float* fcw  = (const float*)d_in[15];
  const float* fcb  = (const float*)d_in[16];
  const float* bng  = (const float*)d_in[17];
  const float* bnb  = (const float*)d_in[18];
  const float* bnm  = (const float*)d_in[19];
  const float* bnv  = (const float*)d_in[20];
  const float* nhw1 = (const float*)d_in[21];
  const float* nhb1 = (const float*)d_in[22];
  const float* nhw2 = (const float*)d_in[23];
  const float* nhb2 = (const float*)d_in[24];
  const float* dhw1 = (const float*)d_in[25];
  const float* dhb1 = (const float*)d_in[26];
  const float* dhw2 = (const float*)d_in[27];
  const float* dhb2 = (const float*)d_in[28];
  const float* wtw1 = (const float*)d_in[29];
  const float* wtb1 = (const float*)d_in[30];
  const float* wtw2 = (const float*)d_in[31];
  const float* wtb2 = (const float*)d_in[32];
  short* ws  = (short*)d_ws;
  float* out = (float*)d_out;

  prep_weights<<<(int)((WS_TOTAL + 255)/256), 256, 0, stream>>>(
      pbw, paw1, piw1, pfw, pgw, fcw, nhw1, nhw2, dhw1, dhw2, wtw1, ws);
  pan_main<<<512, 512, 0, stream>>>(
      x, pbb, pab1, paw2, pab2, pib1, piw2, pib2, pfb, pgb, fcb,
      bng, bnb, bnm, bnv, nhb1, nhb2, dhb1, dhb2, wtb1, wtw2, wtb2, ws, out);
}

// Round 10
// 326.938 us; speedup vs baseline: 1.1423x; 1.0097x over previous
//
#include <hip/hip_runtime.h>

#define DI __device__ __forceinline__

typedef short bf16x8 __attribute__((ext_vector_type(8)));
typedef float f32x4  __attribute__((ext_vector_type(4)));

#define MFMA(a,b,c) __builtin_amdgcn_mfma_f32_16x16x32_bf16(a,b,c,0,0,0)

constexpr int    SZ_WT = 512*80;
constexpr int    SZ_WB = 512*96;
constexpr int    SZ_WF = 96*512;
constexpr int    SZ_WG = 512*512;
constexpr int    SZ_WC = 512*512;
constexpr size_t OFF_WT  = 0;
constexpr size_t OFF_WB  = OFF_WT + 3*(size_t)SZ_WT;     // 122880
constexpr size_t OFF_WF  = OFF_WB + 3*(size_t)SZ_WB;     // 270336
constexpr size_t OFF_WG  = OFF_WF + 3*(size_t)SZ_WF;     // 417792
constexpr size_t OFF_WC  = OFF_WG + 3*(size_t)SZ_WG;     // 1204224
constexpr size_t OFF_WH  = OFF_WC + 3*(size_t)SZ_WC;     // 1990656  [512][192] nhw1|dhw1|wtw1
constexpr size_t OFF_WH2 = OFF_WH + (size_t)512*192;     // 2088960  [128][256] blockdiag(nhw2,dhw2)
constexpr size_t WS_TOTAL= OFF_WH2 + (size_t)128*256;    // 2121728 bf16 elems

DI short f2b(float f){ unsigned u; __builtin_memcpy(&u,&f,4); u += 0x7fffu + ((u>>16)&1u); return (short)(u>>16); }
DI float b2f(short s){ unsigned u = ((unsigned)(unsigned short)s)<<16; float f; __builtin_memcpy(&f,&u,4); return f; }
DI float sigm(float x){ return 1.f/(1.f+__expf(-x)); }
DI unsigned pk2(float a, float b){
  return (unsigned)(unsigned short)f2b(a) | ((unsigned)(unsigned short)f2b(b) << 16);
}

// ---------------- weight prepass: fp32 -> bf16 MFMA-B-fragment layout ----------------
// frag element t = ((nt*K32 + kt)*64 + lane)*8 + j  <->  W[kt*32 + (lane>>4)*8 + j][nt*16 + (lane&15)]
__global__ __launch_bounds__(256) void prep_weights(
    const float* __restrict__ pbw,  const float* __restrict__ paw1,
    const float* __restrict__ piw1, const float* __restrict__ pfw,
    const float* __restrict__ pgw,  const float* __restrict__ fcw,
    const float* __restrict__ nhw1, const float* __restrict__ nhw2,
    const float* __restrict__ dhw1, const float* __restrict__ dhw2,
    const float* __restrict__ wtw1, short* __restrict__ ws)
{
  size_t t = (size_t)blockIdx.x*256 + threadIdx.x;
  if (t >= WS_TOTAL) return;
  float v = 0.f;
  if (t < OFF_WB) {                                   // [512][80] = paw1 | piw1, K32=16
    int q=(int)t; int ly=q/SZ_WT; int qq=q%SZ_WT;
    int j=qq&7, lane=(qq>>3)&63, tile=qq>>9, kt=tile&15, nt=tile>>4;
    int k=kt*32+((lane>>4)<<3)+j, n=nt*16+(lane&15);
    v = (n<64) ? paw1[((size_t)ly*512+k)*64+n] : piw1[((size_t)ly*512+k)*16+(n-64)];
  } else if (t < OFF_WF) {                            // [512][96] pbw flat (c=k*32+j), K32=16
    int q=(int)(t-OFF_WB); int ly=q/SZ_WB; int qq=q%SZ_WB;
    int j=qq&7, lane=(qq>>3)&63, tile=qq>>9, kt=tile&15, nt=tile>>4;
    int k=kt*32+((lane>>4)<<3)+j, c=nt*16+(lane&15);
    v = pbw[(((size_t)ly*3+(c>>5))*512+k)*32+(c&31)];
  } else if (t < OFF_WG) {                            // [96][512] pfw, K32=3
    int q=(int)(t-OFF_WF); int ly=q/SZ_WF; int qq=q%SZ_WF;
    int j=qq&7, lane=(qq>>3)&63, tile=qq>>9, kt=tile%3, nt=tile/3;
    int k=kt*32+((lane>>4)<<3)+j, n=nt*16+(lane&15);
    v = pfw[((size_t)ly*96+k)*512+n];
  } else if (t < OFF_WC) {                            // [512][512] pgw
    int q=(int)(t-OFF_WG); int ly=q/SZ_WG; int qq=q%SZ_WG;
    int j=qq&7, lane=(qq>>3)&63, tile=qq>>9, kt=tile&15, nt=tile>>4;
    int k=kt*32+((lane>>4)<<3)+j, n=nt*16+(lane&15);
    v = pgw[((size_t)ly*512+k)*512+n];
  } else if (t < OFF_WH) {                            // [512][512] fcw
    int q=(int)(t-OFF_WC); int ly=q/SZ_WC; int qq=q%SZ_WC;
    int j=qq&7, lane=(qq>>3)&63, tile=qq>>9, kt=tile&15, nt=tile>>4;
    int k=kt*32+((lane>>4)<<3)+j, n=nt*16+(lane&15);
    v = fcw[((size_t)ly*512+k)*512+n];
  } else if (t < OFF_WH2) {                           // [512][192] heads hidden
    int qq=(int)(t-OFF_WH);
    int j=qq&7, lane=(qq>>3)&63, tile=qq>>9, kt=tile&15, nt=tile>>4;
    int k=kt*32+((lane>>4)<<3)+j, n=nt*16+(lane&15);
    v = (n<64) ? nhw1[(size_t)k*64+n] : (n<128) ? dhw1[(size_t)k*64+(n-64)] : wtw1[(size_t)k*64+(n-128)];
  } else {                                            // [128][256] blockdiag(nhw2,dhw2), K32=4
    int qq=(int)(t-OFF_WH2);
    int j=qq&7, lane=(qq>>3)&63, tile=qq>>9, kt=tile&3, nt=tile>>2;
    int k=kt*32+((lane>>4)<<3)+j, n=nt*16+(lane&15);
    if (k<64) v = (n<128) ? nhw2[(size_t)k*128+n] : 0.f;
    else      v = (n>=128)? dhw2[(size_t)(k-64)*128+(n-128)] : 0.f;
  }
  ws[t] = f2b(v);
}

// ---------------- fused network ----------------
// 64 rows/block, 512 threads (8 waves), LDS=80KB -> 2 blocks/CU = 4 waves/EU.
// amdgpu_waves_per_eu(4,4) pins the RA occupancy target to exactly 4 waves/EU
// (128-VGPR budget). NOTE: __launch_bounds__'s 2nd arg is only a MIN — the
// backend's memory-bound heuristic then picks 8 waves/EU (64 VGPR) and spills
// (R9: 200MB/side scratch). All local arrays statically indexed (rule #20).
__global__ __attribute__((amdgpu_flat_work_group_size(512,512), amdgpu_waves_per_eu(4,4)))
void pan_main(
  const float* __restrict__ x,
  const float* __restrict__ pbb,  const float* __restrict__ pab1,
  const float* __restrict__ paw2, const float* __restrict__ pab2,
  const float* __restrict__ pib1, const float* __restrict__ piw2,
  const float* __restrict__ pib2, const float* __restrict__ pfb,
  const float* __restrict__ pgb,  const float* __restrict__ fcb,
  const float* __restrict__ bng,  const float* __restrict__ bnb,
  const float* __restrict__ bnm,  const float* __restrict__ bnv,
  const float* __restrict__ nhb1, const float* __restrict__ nhb2,
  const float* __restrict__ dhb1, const float* __restrict__ dhb2,
  const float* __restrict__ wtb1, const float* __restrict__ wtw2,
  const float* __restrict__ wtb2,
  const short* __restrict__ ws, float* __restrict__ out)
{
  __shared__ __align__(16) char lds[81920];
  char* sH = lds;            // [64][512] bf16, row stride 1024B, byte ^= (row&7)<<4
  char* sU = lds + 65536;    // 16KB union:
                             //  phase A: sT bf16 [64][80] @0 (10240) | ci f32 [64] @10240 | cwci bf16 [64][32] @10496
                             //  phase B: sW bf16 [64][128] swizzled @0 (16384)
                             // heads h1 [64][192] bf16 stride 384 swizzled at lds@0 (sH dead by then)

  const int tid  = threadIdx.x;
  const int wave = tid >> 6;
  const int l    = tid & 63;
  const int lr   = l & 15;
  const int lb   = l >> 4;
  const int swzA = (lr & 7) << 4;
  const size_t row0 = (size_t)blockIdx.x * 64;

  // ---- load x tile -> sH (bf16, swizzled)
  #pragma unroll 2
  for (int c = tid; c < 4096; c += 512) {
    int row = c >> 6, k0 = (c & 63) << 3;
    const float4* s0 = (const float4*)(x + (row0 + row)*512 + k0);
    float4 f0 = s0[0], f1 = s0[1];
    bf16x8 p;
    p[0]=f2b(f0.x); p[1]=f2b(f0.y); p[2]=f2b(f0.z); p[3]=f2b(f0.w);
    p[4]=f2b(f1.x); p[5]=f2b(f1.y); p[6]=f2b(f1.z); p[7]=f2b(f1.w);
    *(bf16x8*)(sH + row*1024 + ((k0*2) ^ ((row&7)<<4))) = p;
  }
  __syncthreads();

  auto ldA = [&](int rt, int kt) -> bf16x8 {
    int row = rt*16 + lr;
    return *(const bf16x8*)(sH + row*1024 + ((kt*64 + lb*16) ^ swzA));
  };
  auto ldB = [&](const short* W, int K32, int nt, int kt) -> bf16x8 {
    return *(const bf16x8*)(W + (((size_t)(nt*K32 + kt))*64 + l)*8);
  };
  auto ldH = [&](int row, int col) -> float {   // scalar bf16 h read (residual term)
    return b2f(*(const short*)(sH + row*1024 + ((col*2) ^ ((row&7)<<4))));
  };
  const f32x4 FZ = {0.f,0.f,0.f,0.f};

  // ================= PAN layers =================
  for (int ly = 0; ly < 3; ++ly) {
    // --- t_all = relu(h @ [paw1|piw1] + b) -> sT  (N=80: waves 0..4)
    if (wave < 5) {
      const short* W = ws + OFF_WT + (size_t)ly*SZ_WT;
      f32x4 acc[4];
      #pragma unroll
      for (int rt=0;rt<4;++rt) acc[rt] = FZ;
      #pragma unroll 2
      for (int kt=0;kt<16;++kt) {
        bf16x8 b = ldB(W,16,wave,kt);
        #pragma unroll
        for (int rt=0;rt<4;++rt) acc[rt] = MFMA(ldA(rt,kt), b, acc[rt]);
      }
      const int col = wave*16 + lr;
      const float bias = (col<64) ? pab1[ly*64+col] : pib1[ly*16+(col-64)];
      #pragma unroll
      for (int rt=0;rt<4;++rt)
        #pragma unroll
        for (int jj=0;jj<4;++jj) {
          int row = rt*16 + lb*4 + jj;
          *(short*)(sU + row*160 + col*2) = f2b(fmaxf(acc[rt][jj]+bias, 0.f));
        }
    }
    __syncthreads();
    // --- ci = sigmoid(t2 @ piw2 + b)  (threads 0..63, vectorized reads)
    if (tid < 64) {
      float s = pib2[ly];
      bf16x8 t0 = *(const bf16x8*)(sU + tid*160 + 128);
      bf16x8 t1 = *(const bf16x8*)(sU + tid*160 + 144);
      #pragma unroll
      for (int i=0;i<8;++i) {
        s += b2f(t0[i]) * piw2[ly*16+i];
        s += b2f(t1[i]) * piw2[ly*16+8+i];
      }
      *(float*)(sU + 10240 + tid*4) = sigm(s);
    }
    __syncthreads();
    // --- cwci = sigmoid(t1 @ paw2 + b) * ci  (all 512 thr, 4 outputs/thread)
    {
      const int r = tid>>3, j0 = (tid&7)<<2;
      float a4[4];
      #pragma unroll
      for (int i=0;i<4;++i) a4[i] = pab2[ly*32 + j0 + i];
      #pragma unroll 2
      for (int k8=0;k8<8;++k8) {
        bf16x8 tv8 = *(const bf16x8*)(sU + r*160 + k8*16);
        #pragma unroll
        for (int i8=0;i8<8;++i8) {
          float tv = b2f(tv8[i8]);
          float4 wr = *(const float4*)(paw2 + ((size_t)ly*64 + k8*8+i8)*32 + j0);
          a4[0]=fmaf(tv,wr.x,a4[0]); a4[1]=fmaf(tv,wr.y,a4[1]);
          a4[2]=fmaf(tv,wr.z,a4[2]); a4[3]=fmaf(tv,wr.w,a4[3]);
        }
      }
      const float civ = *(const float*)(sU + 10240 + r*4);
      #pragma unroll
      for (int i=0;i<4;++i)
        *(short*)(sU + 10496 + (r*32 + j0 + i)*2) = f2b(sigm(a4[i]) * civ);
    }
    __syncthreads();
    // --- feats = relu(h @ pbw + b); weighted = feats * cwci  (N=96: waves 0..5)
    unsigned wpk[4][2];
    if (wave < 6) {
      const short* W = ws + OFF_WB + (size_t)ly*SZ_WB;
      f32x4 acc[4];
      #pragma unroll
      for (int rt=0;rt<4;++rt) acc[rt] = FZ;
      #pragma unroll 2
      for (int kt=0;kt<16;++kt) {
        bf16x8 b = ldB(W,16,wave,kt);
        #pragma unroll
        for (int rt=0;rt<4;++rt) acc[rt] = MFMA(ldA(rt,kt), b, acc[rt]);
      }
      const int col = wave*16 + lr;
      const float bias = pbb[ly*96 + col];
      #pragma unroll
      for (int rt=0;rt<4;++rt) {
        float w4[4];
        #pragma unroll
        for (int jj=0;jj<4;++jj) {
          int row = rt*16 + lb*4 + jj;
          float cc = b2f(*(const short*)(sU + 10496 + (row*32 + (col&31))*2));
          w4[jj] = fmaxf(acc[rt][jj]+bias, 0.f) * cc;
        }
        wpk[rt][0] = pk2(w4[0], w4[1]);
        wpk[rt][1] = pk2(w4[2], w4[3]);
      }
    }
    __syncthreads();           // all phase-A reads of sU done
    if (wave < 6) {            // weighted -> sW (swizzled, stride 256B)
      const int col = wave*16 + lr;
      #pragma unroll
      for (int rt=0;rt<4;++rt)
        #pragma unroll
        for (int p=0;p<2;++p) {
          int r0 = rt*16 + lb*4 + p*2;
          unsigned v = wpk[rt][p];
          *(short*)(sU + r0*256     + ((col*2) ^ ((r0    &7)<<4))) = (short)(v & 0xffff);
          *(short*)(sU + (r0+1)*256 + ((col*2) ^ (((r0+1)&7)<<4))) = (short)(v >> 16);
        }
    }
    __syncthreads();
    // --- gate = sigmoid(h @ pgw + b); h' = weighted @ pfw + pfb + gate*h
    //     4 cols/wave, 2 fully-unrolled passes of 2 cols. pk indices static.
    unsigned pk[4][4][2];
    {
      const short* Wg = ws + OFF_WG + (size_t)ly*SZ_WG;
      const short* Wf = ws + OFF_WF + (size_t)ly*SZ_WF;
      #pragma unroll
      for (int p=0; p<2; ++p) {
        f32x4 acc[4][2];
        #pragma unroll
        for (int rt=0;rt<4;++rt) { acc[rt][0]=FZ; acc[rt][1]=FZ; }
        #pragma unroll 2
        for (int kt=0;kt<16;++kt) {
          bf16x8 b0 = ldB(Wg,16, wave*4+p*2+0, kt);
          bf16x8 b1 = ldB(Wg,16, wave*4+p*2+1, kt);
          #pragma unroll
          for (int rt=0;rt<4;++rt) {
            bf16x8 a = ldA(rt,kt);
            acc[rt][0] = MFMA(a,b0,acc[rt][0]);
            acc[rt][1] = MFMA(a,b1,acc[rt][1]);
          }
        }
        #pragma unroll
        for (int c2=0;c2<2;++c2) {
          const int col = (wave*4+p*2+c2)*16 + lr;
          const float gb = pgb[ly*512+col];
          const float fb = pfb[ly*512+col];
          #pragma unroll
          for (int rt=0;rt<4;++rt)
            #pragma unroll
            for (int jj=0;jj<4;++jj) {
              int row = rt*16 + lb*4 + jj;
              acc[rt][c2][jj] = sigm(acc[rt][c2][jj]+gb)*ldH(row,col) + fb;
            }
        }
        #pragma unroll 1
        for (int kt=0;kt<3;++kt) {   // fused accumulate, K=96, A from sW
          bf16x8 b0 = ldB(Wf,3, wave*4+p*2+0, kt);
          bf16x8 b1 = ldB(Wf,3, wave*4+p*2+1, kt);
          #pragma unroll
          for (int rt=0;rt<4;++rt) {
            int row = rt*16 + lr;
            bf16x8 a = *(const bf16x8*)(sU + row*256 + ((kt*64 + lb*16) ^ swzA));
            acc[rt][0] = MFMA(a,b0,acc[rt][0]);
            acc[rt][1] = MFMA(a,b1,acc[rt][1]);
          }
        }
        #pragma unroll
        for (int c2=0;c2<2;++c2)
          #pragma unroll
          for (int rt=0;rt<4;++rt) {
            pk[p*2+c2][rt][0] = pk2(acc[rt][c2][0], acc[rt][c2][1]);
            pk[p*2+c2][rt][1] = pk2(acc[rt][c2][2], acc[rt][c2][3]);
          }
      }
    }
    __syncthreads();           // all reads of old h / sW complete
    #pragma unroll
    for (int ci2=0;ci2<4;++ci2) {   // publish h' bf16
      const int col = (wave*4+ci2)*16 + lr;
      #pragma unroll
      for (int rt=0;rt<4;++rt)
        #pragma unroll
        for (int q=0;q<2;++q) {
          int r0 = rt*16 + lb*4 + q*2;
          unsigned v = pk[ci2][rt][q];
          *(short*)(sH + r0*1024     + ((col*2) ^ ((r0    &7)<<4))) = (short)(v & 0xffff);
          *(short*)(sH + (r0+1)*1024 + ((col*2) ^ (((r0+1)&7)<<4))) = (short)(v >> 16);
        }
    }
    __syncthreads();
  }

  // ================= FC + BN(eval) + ReLU  x3 =================
  for (int fi=0; fi<3; ++fi) {
    const short* W = ws + OFF_WC + (size_t)fi*SZ_WC;
    unsigned pk[4][4][2];
    #pragma unroll
    for (int p=0; p<2; ++p) {
      f32x4 acc[4][2];
      #pragma unroll
      for (int rt=0;rt<4;++rt) { acc[rt][0]=FZ; acc[rt][1]=FZ; }
      #pragma unroll 2
      for (int kt=0;kt<16;++kt) {
        bf16x8 b0 = ldB(W,16, wave*4+p*2+0, kt);
        bf16x8 b1 = ldB(W,16, wave*4+p*2+1, kt);
        #pragma unroll
        for (int rt=0;rt<4;++rt) {
          bf16x8 a = ldA(rt,kt);
          acc[rt][0] = MFMA(a,b0,acc[rt][0]);
          acc[rt][1] = MFMA(a,b1,acc[rt][1]);
        }
      }
      #pragma unroll
      for (int c2=0;c2<2;++c2) {
        const int col = (wave*4+p*2+c2)*16 + lr;
        const float sc = bng[fi*512+col] * rsqrtf(bnv[fi*512+col] + 1e-5f);
        const float of = bnb[fi*512+col] - bnm[fi*512+col]*sc;
        const float bb = fcb[fi*512+col];
        #pragma unroll
        for (int rt=0;rt<4;++rt) {
          float z0 = fmaxf((acc[rt][c2][0] + bb)*sc + of, 0.f);
          float z1 = fmaxf((acc[rt][c2][1] + bb)*sc + of, 0.f);
          float z2 = fmaxf((acc[rt][c2][2] + bb)*sc + of, 0.f);
          float z3 = fmaxf((acc[rt][c2][3] + bb)*sc + of, 0.f);
          pk[p*2+c2][rt][0] = pk2(z0, z1);
          pk[p*2+c2][rt][1] = pk2(z2, z3);
        }
      }
    }
    __syncthreads();
    #pragma unroll
    for (int ci2=0;ci2<4;++ci2) {
      const int col = (wave*4+ci2)*16 + lr;
      #pragma unroll
      for (int rt=0;rt<4;++rt)
        #pragma unroll
        for (int q=0;q<2;++q) {
          int r0 = rt*16 + lb*4 + q*2;
          unsigned v = pk[ci2][rt][q];
          *(short*)(sH + r0*1024     + ((col*2) ^ ((r0    &7)<<4))) = (short)(v & 0xffff);
          *(short*)(sH + (r0+1)*1024 + ((col*2) ^ (((r0+1)&7)<<4))) = (short)(v >> 16);
        }
    }
    __syncthreads();
  }

  // ================= heads =================
  // h1 = relu(h @ [nhw1|dhw1|wtw1] + b): N=192 = 12 tiles; wave does tile
  // `wave` (A) and, for wave<4, tile 8+wave (B). Held in regs across barrier.
  unsigned hkA[4][2], hkB[4][2];
  {
    const short* W = ws + OFF_WH;
    {
      f32x4 acc[4];
      #pragma unroll
      for (int rt=0;rt<4;++rt) acc[rt] = FZ;
      #pragma unroll 2
      for (int kt=0;kt<16;++kt) {
        bf16x8 b = ldB(W,16,wave,kt);
        #pragma unroll
        for (int rt=0;rt<4;++rt) acc[rt] = MFMA(ldA(rt,kt), b, acc[rt]);
      }
      const int col = wave*16 + lr;
      const float bias = (col<64) ? nhb1[col] : dhb1[col-64];
      #pragma unroll
      for (int rt=0;rt<4;++rt) {
        hkA[rt][0] = pk2(fmaxf(acc[rt][0]+bias,0.f), fmaxf(acc[rt][1]+bias,0.f));
        hkA[rt][1] = pk2(fmaxf(acc[rt][2]+bias,0.f), fmaxf(acc[rt][3]+bias,0.f));
      }
    }
    if (wave < 4) {
      f32x4 acc[4];
      #pragma unroll
      for (int rt=0;rt<4;++rt) acc[rt] = FZ;
      #pragma unroll 2
      for (int kt=0;kt<16;++kt) {
        bf16x8 b = ldB(W,16, 8+wave, kt);
        #pragma unroll
        for (int rt=0;rt<4;++rt) acc[rt] = MFMA(ldA(rt,kt), b, acc[rt]);
      }
      const int col = (8+wave)*16 + lr;   // 128..191 -> wait-head hidden
      const float bias = wtb1[col-128];
      #pragma unroll
      for (int rt=0;rt<4;++rt) {
        hkB[rt][0] = pk2(fmaxf(acc[rt][0]+bias,0.f), fmaxf(acc[rt][1]+bias,0.f));
        hkB[rt][1] = pk2(fmaxf(acc[rt][2]+bias,0.f), fmaxf(acc[rt][3]+bias,0.f));
      }
    }
  }
  __syncthreads();             // sH reads done
  {                            // h1 -> lds@0, [64][192] stride 384B, swizzled
    #pragma unroll
    for (int rt=0;rt<4;++rt)
      #pragma unroll
      for (int q=0;q<2;++q) {
        int r0 = rt*16 + lb*4 + q*2;
        int cA = wave*16 + lr;
        unsigned v = hkA[rt][q];
        *(short*)(lds + r0*384     + ((cA*2) ^ ((r0    &7)<<4))) = (short)(v & 0xffff);
        *(short*)(lds + (r0+1)*384 + ((cA*2) ^ (((r0+1)&7)<<4))) = (short)(v >> 16);
      }
    if (wave < 4) {
      #pragma unroll
      for (int rt=0;rt<4;++rt)
        #pragma unroll
        for (int q=0;q<2;++q) {
          int r0 = rt*16 + lb*4 + q*2;
          int cB = (8+wave)*16 + lr;
          unsigned v = hkB[rt][q];
          *(short*)(lds + r0*384     + ((cB*2) ^ ((r0    &7)<<4))) = (short)(v & 0xffff);
          *(short*)(lds + (r0+1)*384 + ((cB*2) ^ (((r0+1)&7)<<4))) = (short)(v >> 16);
        }
    }
  }
  __syncthreads();
  { // logits = h1[:, :128] @ blockdiag(nhw2,dhw2): 16 tiles = 8 waves x 2
    const short* W2 = ws + OFF_WH2;
    #pragma unroll
    for (int p=0;p<2;++p) {
      f32x4 acc[4];
      #pragma unroll
      for (int rt=0;rt<4;++rt) acc[rt] = FZ;
      #pragma unroll 2
      for (int kt=0;kt<4;++kt) {
        bf16x8 b = ldB(W2,4, wave*2+p, kt);
        #pragma unroll
        for (int rt=0;rt<4;++rt) {
          int row = rt*16 + lr;
          bf16x8 a = *(const bf16x8*)(lds + row*384 + ((kt*64 + lb*16) ^ swzA));
          acc[rt] = MFMA(a,b,acc[rt]);
        }
      }
      const int col2 = (wave*2+p)*16 + lr;
      const bool isn = col2 < 128;
      const int cc = col2 & 127;
      const float bias = isn ? nhb2[cc] : dhb2[cc];
      const size_t obase = isn ? (size_t)0 : (size_t)4194304;
      #pragma unroll
      for (int rt=0;rt<4;++rt)
        #pragma unroll
        for (int jj=0;jj<4;++jj) {
          int row = rt*16 + lb*4 + jj;
          size_t rg = row0 + row;
          float2 caps = *(const float2*)(x + rg*512 + 508);   // (s_nurse_max, s_doctor_max)
          int cap = (int)(isn ? caps.x : caps.y);
          float v = acc[rt][jj] + bias;
          out[obase + rg*128 + cc] = (cc <= cap) ? v : -1e9f;
        }
    }
  }
  // wait_time = h1[:, 128:192] @ wtw2 + b (read-only on h1)
  if (tid < 64) {
    float s = wtb2[0];
    #pragma unroll 2
    for (int k8=0;k8<8;++k8) {
      bf16x8 hv = *(const bf16x8*)(lds + tid*384 + ((256 + k8*16) ^ ((tid&7)<<4)));
      #pragma unroll
      for (int i=0;i<8;++i) s += b2f(hv[i]) * wtw2[k8*8+i];
    }
    out[(size_t)8388608 + row0 + tid] = s;
  }
}

extern "C" void kernel_launch(void* const* d_in, const int* in_sizes, int n_in,
                              void* d_out, int out_size, void* d_ws, size_t ws_size,
                              hipStream_t stream) {
  const float* x    = (const float*)d_in[0];
  const float* pbw  = (const float*)d_in[1];
  const float* pbb  = (const float*)d_in[2];
  const float* paw1 = (const float*)d_in[3];
  const float* pab1 = (const float*)d_in[4];
  const float* paw2 = (const float*)d_in[5];
  const float* pab2 = (const float*)d_in[6];
  const float* piw1 = (const float*)d_in[7];
  const float* pib1 = (const float*)d_in[8];
  const float* piw2 = (const float*)d_in[9];
  const float* pib2 = (const float*)d_in[10];
  const float* pfw  = (const float*)d_in[11];
  const float* pfb  = (const float*)d_in[12];
  const float* pgw  = (const float*)d_in[13];
  const float* pgb  = (const float*)d_in[14];
  const float* fcw  = (const float*)d_in[15];
  const float* fcb  = (const float*)d_in[16];
  const float* bng  = (const float*)d_in[17];
  const float* bnb  = (const float*)d_in[18];
  const float* bnm  = (const float*)d_in[19];
  const float* bnv  = (const float*)d_in[20];
  const float* nhw1 = (const float*)d_in[21];
  const float* nhb1 = (const float*)d_in[22];
  const float* nhw2 = (const float*)d_in[23];
  const float* nhb2 = (const float*)d_in[24];
  const float* dhw1 = (const float*)d_in[25];
  const float* dhb1 = (const float*)d_in[26];
  const float* dhw2 = (const float*)d_in[27];
  const float* dhb2 = (const float*)d_in[28];
  const float* wtw1 = (const float*)d_in[29];
  const float* wtb1 = (const float*)d_in[30];
  const float* wtw2 = (const float*)d_in[31];
  const float* wtb2 = (const float*)d_in[32];
  short* ws  = (short*)d_ws;
  float* out = (float*)d_out;

  prep_weights<<<(int)((WS_TOTAL + 255)/256), 256, 0, stream>>>(
      pbw, paw1, piw1, pfw, pgw, fcw, nhw1, nhw2, dhw1, dhw2, wtw1, ws);
  pan_main<<<512, 512, 0, stream>>>(
      x, pbb, pab1, paw2, pab2, pib1, piw2, pib2, pfb, pgb, fcb,
      bng, bnb, bnm, bnv, nhb1, nhb2, dhb1, dhb2, wtb1, wtw2, wtb2, ws, out);
}